// Round 8
// baseline (5917.223 us; speedup 1.0000x reference)
//
#include <hip/hip_runtime.h>
#include <hip/hip_bf16.h>

// ---------------------------------------------------------------------------
// v5: Fused LSTM (B=32,T=2048,I=128,H=512,O=128), one persistent kernel.
//
// Change vs v4: EPOCH TAGS replace canary+restore. Payload u64 =
// (c_fp32 with low 2 mantissa bits = tag) << 32 | (h_hi16<<16 | h_lo16).
// tag = ((t>>2)+1)&3. MALL holds only the LAST store per slot, and WG lag
// is < 4 steps (poll lockstep), so tag mismatch <=> stale. This removes:
// all canary-restore stores (half the fabric store traffic), wave7's
// restore + vmcnt stall, and the ENTIRE one-time init (tag offset +1 makes
// 0xAA poison (tag 2), zeros (tag 0), and prior-launch residue (late-step
// tags = 0) all mismatch t=0's expected tag 1). Tag bits live in c, which
// feeds ONLY the decode (error 2^-22); recurrent c stays fp32 in wave0
// registers; h is untouched.
//
// Poll loads are issued EARLY (right after the MFMA inner loop, before
// B1/role) so they fly under the barrier + role work.
//
// Roles per step: all 8 waves MFMA; wave0 = cell update + tagged store;
// waves1-4 = decode t-1; waves5-6 = x-stage + prefetch; wave7 idle.
// Then all waves poll-check + unpack to LDS. 2 lgkm-only barriers/step.
// ---------------------------------------------------------------------------

#define B_ 32
#define T_ 2048
#define I_ 128
#define H_ 512
#define O_ 128
#define NG 8     // batch groups
#define BPG 4    // batches per group
#define WPG 32   // workgroups per group
#define NWG 256
#define NTHR 512
#define NBUF 4

#define HXS 656  // LDS [h|x] row stride (bf16), 640 data + 16 pad (bank-opt)
#define CPS 520  // LDS c_prev / lin_W row stride (floats), 512 + 8 pad

typedef short bf16x8 __attribute__((ext_vector_type(8)));
typedef float f32x4 __attribute__((ext_vector_type(4)));
typedef unsigned long long u64;

static __device__ __forceinline__ unsigned f2bf(float f) {
  unsigned u = __float_as_uint(f);
  u = u + 0x7FFFu + ((u >> 16) & 1u);  // RNE
  return u >> 16;
}
static __device__ __forceinline__ float bf2f(unsigned h) {
  return __uint_as_float(h << 16);
}
static __device__ __forceinline__ float fsigm(float x) {
  return 1.0f / (1.0f + __expf(-x));
}
static __device__ __forceinline__ float ftanh(float x) {
  return 1.0f - 2.0f / (__expf(2.0f * x) + 1.0f);  // safe at +-inf
}

#define ALD(p) __hip_atomic_load((p), __ATOMIC_RELAXED, __HIP_MEMORY_SCOPE_AGENT)
#define AST(p, v) __hip_atomic_store((p), (v), __ATOMIC_RELAXED, __HIP_MEMORY_SCOPE_AGENT)
// Raw workgroup barrier: LDS-drain only, no vmcnt(0) store-ACK serialization.
#define BARRIER() asm volatile("s_waitcnt lgkmcnt(0)\ns_barrier" ::: "memory")

__global__ __launch_bounds__(NTHR, 2) void lstm_fused(
    const float* __restrict__ data, const float* __restrict__ h0,
    const float* __restrict__ c0, const float* __restrict__ W_ih,
    const float* __restrict__ W_hh, const float* __restrict__ b_ih,
    const float* __restrict__ b_hh, const float* __restrict__ lin_W,
    const float* __restrict__ lin_b, float* __restrict__ out,
    float* __restrict__ ws) {
  __shared__ alignas(16) unsigned short sHxHi[BPG * HXS];
  __shared__ alignas(16) unsigned short sHxLo[BPG * HXS];
  __shared__ alignas(16) float sCp[2][BPG * CPS];  // c double-buffer (decode)
  __shared__ alignas(16) float sLinW[4 * CPS];
  __shared__ alignas(16) float sGates[4][2][68];   // [gate][kh][up*4+b]
  __shared__ float sLinB[4];

  const int bid = blockIdx.x;
  const int g = bid & 7;       // batch group
  const int wgi = bid >> 3;    // 0..31 within group
  const int b0 = g * BPG;
  const int ubase = wgi * 16;  // hidden-unit base
  const int tid = threadIdx.x;
  const int lane = tid & 63;
  const int w = tid >> 6;      // wave 0..7
  const int gate = w >> 1;     // i,f,g,o
  const int kh = w & 1;        // K half
  const int m16 = lane & 15;   // MFMA col = batch
  const int kcg = lane >> 4;

  u64* hcPk = (u64*)ws;  // [NBUF][NG][BPG][H] u64 slots (tagged c<<32 | h_pk)

  // ---- one-time preload ----
  bf16x8 fAhi[10], fAlo[10];
  const int grow = gate * H_ + ubase + m16;
#pragma unroll
  for (int kk = 0; kk < 10; kk++) {
    int k = kh * 320 + kk * 32 + kcg * 8;
    const float* src = (k < H_) ? (W_hh + (size_t)grow * H_ + k)
                                : (W_ih + (size_t)grow * I_ + (k - H_));
    float4 v0 = *(const float4*)src;
    float4 v1 = *(const float4*)(src + 4);
    float w8[8] = {v0.x, v0.y, v0.z, v0.w, v1.x, v1.y, v1.z, v1.w};
    union { unsigned short u[8]; bf16x8 v; } hi, lo;
#pragma unroll
    for (int j = 0; j < 8; j++) {
      unsigned h = f2bf(w8[j]);
      hi.u[j] = (unsigned short)h;
      lo.u[j] = (unsigned short)f2bf(w8[j] - bf2f(h));
    }
    fAhi[kk] = hi.v;
    fAlo[kk] = lo.v;
  }
  float bias_[4], c_state = 0.f;
  if (tid < 64) {  // wave0: per-thread (up,b) bias + c-state in registers
    int up = tid >> 2, b = tid & 3;
#pragma unroll
    for (int ga = 0; ga < 4; ga++) {
      int r = ga * H_ + ubase + up;
      bias_[ga] = b_ih[r] + b_hh[r];
    }
    c_state = c0[(size_t)(b0 + b) * H_ + ubase + up];
  }
  for (int idx = tid; idx < 4 * H_; idx += NTHR) {
    int o = idx >> 9, k = idx & (H_ - 1);
    sLinW[o * CPS + k] = lin_W[(size_t)(wgi * 4 + o) * H_ + k];
  }
  if (tid < 4) sLinB[tid] = lin_b[wgi * 4 + tid];

  // stage h0 (split bf16) and x0
  if (tid < 256) {
    int b = tid >> 6, off = (tid & 63) * 8;
    const float* src = h0 + (size_t)(b0 + b) * H_ + off;
    float4 v0 = *(const float4*)src;
    float4 v1 = *(const float4*)(src + 4);
    float w8[8] = {v0.x, v0.y, v0.z, v0.w, v1.x, v1.y, v1.z, v1.w};
    union { unsigned short u[8]; uint4 q; } hi, lo;
#pragma unroll
    for (int j = 0; j < 8; j++) {
      unsigned h = f2bf(w8[j]);
      hi.u[j] = (unsigned short)h;
      lo.u[j] = (unsigned short)f2bf(w8[j] - bf2f(h));
    }
    *(uint4*)&sHxHi[b * HXS + off] = hi.q;
    *(uint4*)&sHxLo[b * HXS + off] = lo.q;
  }
  if (tid >= 256 && tid < 384) {
    int i = tid - 256, b = i >> 5, c4 = i & 31;
    float4 v = *(const float4*)(data + ((size_t)(b0 + b) * T_) * I_ + c4 * 4);
    float w4[4] = {v.x, v.y, v.z, v.w};
    union { unsigned short u[4]; uint2 q; } hi, lo;
#pragma unroll
    for (int j = 0; j < 4; j++) {
      unsigned h = f2bf(w4[j]);
      hi.u[j] = (unsigned short)h;
      lo.u[j] = (unsigned short)f2bf(w4[j] - bf2f(h));
    }
    *(uint2*)&sHxHi[b * HXS + H_ + c4 * 4] = hi.q;
    *(uint2*)&sHxLo[b * HXS + H_ + c4 * 4] = lo.q;
  }
  float4 pfx;
  if (tid >= 320 && tid < 448) {  // pfx = x_1
    int i = tid - 320, b = i >> 5, c4 = i & 31;
    int tp = (T_ > 1) ? 1 : 0;
    pfx = *(const float4*)(data + ((size_t)(b0 + b) * T_ + tp) * I_ + c4 * 4);
  }
  __syncthreads();

  const int bcl = (m16 < BPG) ? m16 : (BPG - 1);
  const unsigned short* pBhi = sHxHi + bcl * HXS + kh * 320 + kcg * 8;
  const unsigned short* pBlo = sHxLo + bcl * HXS + kh * 320 + kcg * 8;

  for (int t = 0; t < T_; t++) {
    const unsigned tag = (unsigned)(((t >> 2) + 1) & 3);
    // ---- MFMA: partial gates for (gate, kh) on staged [h_{t-1}|x_t] ----
    f32x4 a0 = {0.f, 0.f, 0.f, 0.f}, a1 = a0, a2 = a0;
#pragma unroll
    for (int kk = 0; kk < 10; kk++) {
      bf16x8 bh = *(const bf16x8*)(pBhi + kk * 32);
      bf16x8 bl = *(const bf16x8*)(pBlo + kk * 32);
      a0 = __builtin_amdgcn_mfma_f32_16x16x32_bf16(fAhi[kk], bh, a0, 0, 0, 0);
      a1 = __builtin_amdgcn_mfma_f32_16x16x32_bf16(fAhi[kk], bl, a1, 0, 0, 0);
      a2 = __builtin_amdgcn_mfma_f32_16x16x32_bf16(fAlo[kk], bh, a2, 0, 0, 0);
    }

    // ---- EARLY poll-load issue (fly under B1 + role work) ----
    const int sb = tid >> 7;
    const int su4 = (tid & 127) * 4;
    const u64* sp = hcPk + (((size_t)(t & 3) * NG + g) * BPG + sb) * H_ + su4;
    u64 v0 = ALD(sp), v1 = ALD(sp + 1), v2 = ALD(sp + 2), v3 = ALD(sp + 3);

    if (m16 < BPG) {  // C: col=m16(batch), row=kcg*4+j (=up)
#pragma unroll
      for (int j = 0; j < 4; j++) {
        sGates[gate][kh][kcg * 16 + j * 4 + m16] = a0[j] + a1[j] + a2[j];
      }
    }
    BARRIER();  // B1: sGates ready; all MFMA LDS reads retired

    // ---- role-split phase ----
    if (tid < 64) {
      // cell update + tagged u64 store (no ack wait — data IS the signal)
      int up = tid >> 2, b = tid & 3;
      float gi = sGates[0][0][tid] + sGates[0][1][tid] + bias_[0];
      float gf = sGates[1][0][tid] + sGates[1][1][tid] + bias_[1];
      float gg = sGates[2][0][tid] + sGates[2][1][tid] + bias_[2];
      float go = sGates[3][0][tid] + sGates[3][1][tid] + bias_[3];
      float cn = fsigm(gf) * c_state + fsigm(gi) * ftanh(gg);
      float hn = fsigm(go) * ftanh(cn);
      c_state = cn;
      unsigned hh = f2bf(hn);
      unsigned hl = f2bf(hn - bf2f(hh));
      unsigned cbits = (__float_as_uint(cn) & ~3u) | tag;  // tag in c low bits
      u64 pay = ((u64)cbits << 32) | (u64)((hh << 16) | hl);
      AST(&hcPk[(((size_t)(t & 3) * NG + g) * BPG + b) * H_ + ubase + up], pay);
      if (t == T_ - 1) {  // h_f, c_f
        const size_t DEC = (size_t)B_ * T_ * O_;
        out[DEC + (size_t)(b0 + b) * H_ + ubase + up] = hn;
        out[DEC + (size_t)B_ * H_ + (size_t)(b0 + b) * H_ + ubase + up] = cn;
      }
    } else if (tid < 320) {
      // decode step t-1 from sCp[(t-1)&1] (off critical path, LDS only)
      if (t > 0) {
        int q = (tid >> 4) - 4;  // 0..15
        int ks = tid & 15;
        int o = q >> 2, b = q & 3;
        const float* cp = sCp[(t & 1) ^ 1];
        float s = 0.f;
#pragma unroll
        for (int j = 0; j < 32; j++) {
          int k = ks + j * 16;
          s += sLinW[o * CPS + k] * cp[b * CPS + k];
        }
        s += __shfl_xor(s, 1);
        s += __shfl_xor(s, 2);
        s += __shfl_xor(s, 4);
        s += __shfl_xor(s, 8);
        if (ks == 0)
          out[((size_t)(b0 + b) * T_ + (t - 1)) * O_ + wgi * 4 + o] =
              s + sLinB[o];
      }
    } else if (tid < 448) {
      // stage x_{t+1} from pfx (safe: B1 passed); prefetch x_{t+2}
      int i = tid - 320, b = i >> 5, c4 = i & 31;
      union { unsigned short u[4]; uint2 q; } hi, lo;
      float w4[4] = {pfx.x, pfx.y, pfx.z, pfx.w};
#pragma unroll
      for (int j = 0; j < 4; j++) {
        unsigned h = f2bf(w4[j]);
        hi.u[j] = (unsigned short)h;
        lo.u[j] = (unsigned short)f2bf(w4[j] - bf2f(h));
      }
      *(uint2*)&sHxHi[b * HXS + H_ + c4 * 4] = hi.q;
      *(uint2*)&sHxLo[b * HXS + H_ + c4 * 4] = lo.q;
      int tp = (t + 2 < T_) ? t + 2 : T_ - 1;
      pfx = *(const float4*)(data + ((size_t)(b0 + b) * T_ + tp) * I_ + c4 * 4);
    }
    // wave7: no role — straight to poll

    // ---- poll: tag-check (early loads first), then unpack to LDS ----
    for (;;) {
      bool bad = (((unsigned)(v0 >> 32) & 3) != tag) |
                 (((unsigned)(v1 >> 32) & 3) != tag) |
                 (((unsigned)(v2 >> 32) & 3) != tag) |
                 (((unsigned)(v3 >> 32) & 3) != tag);
      if (!bad) break;
      v0 = ALD(sp);
      v1 = ALD(sp + 1);
      v2 = ALD(sp + 2);
      v3 = ALD(sp + 3);
    }
    {
      unsigned p0 = (unsigned)v0, p1 = (unsigned)v1, p2 = (unsigned)v2,
               p3 = (unsigned)v3;
      uint2 hw = {(p0 >> 16) | (p1 & 0xFFFF0000u),
                  (p2 >> 16) | (p3 & 0xFFFF0000u)};
      uint2 lw = {(p0 & 0xFFFFu) | (p1 << 16),
                  (p2 & 0xFFFFu) | (p3 << 16)};
      *(uint2*)&sHxHi[sb * HXS + su4] = hw;
      *(uint2*)&sHxLo[sb * HXS + su4] = lw;
      float4 cf = {__uint_as_float((unsigned)(v0 >> 32) & ~3u),
                   __uint_as_float((unsigned)(v1 >> 32) & ~3u),
                   __uint_as_float((unsigned)(v2 >> 32) & ~3u),
                   __uint_as_float((unsigned)(v3 >> 32) & ~3u)};
      *(float4*)&sCp[t & 1][sb * CPS + su4] = cf;
    }
    BARRIER();  // B2: sHxHi/Lo + sCp ready for next step
  }

  // ---- epilogue: decode final step T-1 (sCp[(T-1)&1] holds c_{T-1}) ----
  {
    int q = tid >> 5, ks = tid & 31, o = q >> 2, b = q & 3;
    const float* cp = sCp[(T_ - 1) & 1];
    float s = 0.f;
#pragma unroll
    for (int j = 0; j < 16; j++) {
      int k = ks + j * 32;
      s += sLinW[o * CPS + k] * cp[b * CPS + k];
    }
    s += __shfl_xor(s, 1);
    s += __shfl_xor(s, 2);
    s += __shfl_xor(s, 4);
    s += __shfl_xor(s, 8);
    s += __shfl_xor(s, 16);
    if (ks == 0)
      out[((size_t)(b0 + b) * T_ + (T_ - 1)) * O_ + wgi * 4 + o] =
          s + sLinB[o];
  }
}

extern "C" void kernel_launch(void* const* d_in, const int* in_sizes, int n_in,
                              void* d_out, int out_size, void* d_ws, size_t ws_size,
                              hipStream_t stream) {
  const float* data = (const float*)d_in[0];
  const float* h0 = (const float*)d_in[1];
  const float* c0 = (const float*)d_in[2];
  const float* W_ih = (const float*)d_in[3];
  const float* W_hh = (const float*)d_in[4];
  const float* b_ih = (const float*)d_in[5];
  const float* b_hh = (const float*)d_in[6];
  const float* lin_W = (const float*)d_in[7];
  const float* lin_b = (const float*)d_in[8];
  float* out = (float*)d_out;
  float* ws = (float*)d_ws;

  // No workspace init needed: epoch tags make 0xAA poison (tag 2), zeros
  // (tag 0), and prior-launch residue (tag 0) all mismatch t=0's tag 1.
  hipLaunchKernelGGL(lstm_fused, dim3(NWG), dim3(NTHR), 0, stream, data, h0, c0,
                     W_ih, W_hh, b_ih, b_hh, lin_W, lin_b, out, ws);
}